// Round 3
// baseline (72.644 us; speedup 1.0000x reference)
//
#include <hip/hip_runtime.h>

#define BS 256

__global__ void dir_partials(const float* __restrict__ outputs,
                             const float* __restrict__ targets,
                             float* __restrict__ partials,
                             int n, int P) {
    __shared__ float smem[BS / 64];
    long long stride = (long long)gridDim.x * blockDim.x;
    float acc = 0.f;
    for (long long i = (long long)blockIdx.x * blockDim.x + threadIdx.x; i < n; i += stride) {
        const float4 L  = *reinterpret_cast<const float4*>(targets + i * 8);
        const float4 O  = *reinterpret_cast<const float4*>(outputs + i * 4);
        const float4 Tn = *reinterpret_cast<const float4*>(targets + (i + P) * 8);

        // pred_c = conv_bbox(last + outputs[t])
        float pa = L.x + O.x, pb = L.y + O.y, pc = L.z + O.z, pd = L.w + O.w;
        float Px0 = pa - 0.5f * pc, Py0 = pb - 0.5f * pd, Px1 = pa, Py1 = pb;
        // true_c = conv_bbox(targets[t+1])
        float Tx0 = Tn.x - 0.5f * Tn.z, Ty0 = Tn.y - 0.5f * Tn.w, Tx1 = Tn.x, Ty1 = Tn.y;
        // last_eff: frame 0 -> conv once; frames >=1 -> conv twice (collapsed form)
        float Lx0, Ly0, Lx1, Ly1;
        if (i < P) {
            Lx0 = L.x - 0.5f * L.z; Ly0 = L.y - 0.5f * L.w; Lx1 = L.x; Ly1 = L.y;
        } else {
            Lx0 = 0.5f * (L.x - L.z); Ly0 = 0.5f * (L.y - L.w);
            Lx1 = L.x - 0.5f * L.z;   Ly1 = L.y - 0.5f * L.w;
        }

        // 5 corner points: center, (x0,y0), (x0,y1), (x1,y0), (x1,y1)
        float lxs[5] = {0.5f * (Lx0 + Lx1), Lx0, Lx0, Lx1, Lx1};
        float lys[5] = {0.5f * (Ly0 + Ly1), Ly0, Ly1, Ly0, Ly1};
        float pxs[5] = {0.5f * (Px0 + Px1), Px0, Px0, Px1, Px1};
        float pys[5] = {0.5f * (Py0 + Py1), Py0, Py1, Py0, Py1};
        float txs[5] = {0.5f * (Tx0 + Tx1), Tx0, Tx0, Tx1, Tx1};
        float tys[5] = {0.5f * (Ty0 + Ty1), Ty0, Ty1, Ty0, Ty1};

        #pragma unroll
        for (int k = 0; k < 5; ++k) {
            float pdx = pxs[k] - lxs[k], pdy = pys[k] - lys[k];
            float tdx = txs[k] - lxs[k], tdy = tys[k] - lys[k];
            float pn = sqrtf(pdx * pdx + pdy * pdy) + 1e-6f;
            float tn = sqrtf(tdx * tdx + tdy * tdy) + 1e-6f;
            float cosang = (pdy * tdy + pdx * tdx) / (pn * tn);
            cosang = fminf(1.0f, fmaxf(-1.0f, cosang));
            acc += acosf(cosang);
        }
    }
    // wave64 butterfly + cross-wave LDS reduce
    #pragma unroll
    for (int off = 32; off > 0; off >>= 1) acc += __shfl_down(acc, off, 64);
    int lane = threadIdx.x & 63, w = threadIdx.x >> 6;
    if (lane == 0) smem[w] = acc;
    __syncthreads();
    if (threadIdx.x == 0) {
        float r = 0.f;
        #pragma unroll
        for (int i = 0; i < BS / 64; ++i) r += smem[i];
        partials[blockIdx.x] = r;
    }
}

__global__ void dir_finalize(const float* __restrict__ partials, int nb,
                             float* __restrict__ scalar_out, int P) {
    __shared__ double smem[4];
    double acc = 0.0;
    for (int i = threadIdx.x; i < nb; i += blockDim.x) acc += (double)partials[i];
    #pragma unroll
    for (int off = 32; off > 0; off >>= 1) acc += __shfl_down(acc, off, 64);
    int lane = threadIdx.x & 63, w = threadIdx.x >> 6;
    if (lane == 0) smem[w] = acc;
    __syncthreads();
    if (threadIdx.x == 0) {
        double tot = smem[0] + smem[1] + smem[2] + smem[3];
        *scalar_out = (float)(0.2 * tot / ((double)P * 15.0));
    }
}

__global__ void out_kernel(const float* __restrict__ outputs,
                           const float* __restrict__ targets,
                           const float* __restrict__ scalar_p,
                           float* __restrict__ out,
                           int n, float inv_p) {
    float c = 0.01f * (*scalar_p);
    long long stride = (long long)gridDim.x * blockDim.x;
    for (long long i = (long long)blockIdx.x * blockDim.x + threadIdx.x; i < n; i += stride) {
        const float4 O = *reinterpret_cast<const float4*>(outputs + i * 4);
        const float4 D = *reinterpret_cast<const float4*>(targets + i * 8 + 4);
        float s = 0.f;
        {
            float d = O.x - D.x, ad = fabsf(d);
            s += (ad < 1.f) ? 0.5f * d * d : ad - 0.5f;
        }
        {
            float d = O.y - D.y, ad = fabsf(d);
            s += (ad < 1.f) ? 0.5f * d * d : ad - 0.5f;
        }
        {
            float d = O.z - D.z, ad = fabsf(d);
            s += (ad < 1.f) ? 0.5f * d * d : ad - 0.5f;
        }
        {
            float d = O.w - D.w, ad = fabsf(d);
            s += (ad < 1.f) ? 0.5f * d * d : ad - 0.5f;
        }
        out[i] = 0.99f * s * inv_p + c;
    }
}

extern "C" void kernel_launch(void* const* d_in, const int* in_sizes, int n_in,
                              void* d_out, int out_size, void* d_ws, size_t ws_size,
                              hipStream_t stream) {
    const float* outputs = (const float*)d_in[0];
    const float* targets = (const float*)d_in[1];
    float* out = (float*)d_out;
    float* ws  = (float*)d_ws;

    const int T = 16, F_DIR = 15;
    int P  = in_sizes[0] / (T * 4);    // 200000
    int n1 = F_DIR * P;                // 3,000,000 (t,p) pairs for direction loss
    int n3 = out_size;                 // 16 * P

    const int NB1 = 2048;
    float* partials = ws;              // NB1 floats
    float* scalar   = ws + NB1;        // 1 float

    dir_partials<<<NB1, BS, 0, stream>>>(outputs, targets, partials, n1, P);
    dir_finalize<<<1, 256, 0, stream>>>(partials, NB1, scalar, P);

    int nb3 = (n3 + BS - 1) / BS;
    if (nb3 > 2048) nb3 = 2048;
    out_kernel<<<nb3, BS, 0, stream>>>(outputs, targets, scalar, out, n3, 1.0f / (float)P);
}

// Round 7
// 68.156 us; speedup vs baseline: 1.0658x; 1.0658x over previous
//
#include <hip/hip_runtime.h>

#define BS 256
#define NB1 2048

__device__ __forceinline__ float fast_acos(float x) {
    // Abramowitz & Stegun 4.4.45, branchless; |err| <= ~6.8e-5 rad.
    float ax = fabsf(x);
    float s  = sqrtf(fmaxf(0.f, 1.f - ax));
    float p  = fmaf(ax, fmaf(ax, fmaf(ax, -0.0187293f, 0.0742610f), -0.2121144f), 1.5707288f);
    float r  = s * p;
    return (x >= 0.f) ? r : 3.14159265358979f - r;
}

__global__ void dir_partials(const float* __restrict__ outputs,
                             const float* __restrict__ targets,
                             float* __restrict__ partials,
                             int n, int P) {
    __shared__ float smem[BS / 64];
    long long stride = (long long)gridDim.x * blockDim.x;
    float acc = 0.f;
    for (long long i = (long long)blockIdx.x * blockDim.x + threadIdx.x; i < n; i += stride) {
        const float4 L  = *reinterpret_cast<const float4*>(targets + i * 8);
        const float4 O  = *reinterpret_cast<const float4*>(outputs + i * 4);
        const float4 Tn = *reinterpret_cast<const float4*>(targets + (i + P) * 8);

        // pred_c = conv_bbox(last + outputs[t])
        float pa = L.x + O.x, pb = L.y + O.y, pc = L.z + O.z, pd = L.w + O.w;
        float Px0 = pa - 0.5f * pc, Py0 = pb - 0.5f * pd, Px1 = pa, Py1 = pb;
        // true_c = conv_bbox(targets[t+1])
        float Tx0 = Tn.x - 0.5f * Tn.z, Ty0 = Tn.y - 0.5f * Tn.w, Tx1 = Tn.x, Ty1 = Tn.y;
        // last_eff: frame 0 -> conv once; frames >=1 -> conv twice (collapsed)
        float Lx0, Ly0, Lx1, Ly1;
        if (i < P) {
            Lx0 = L.x - 0.5f * L.z; Ly0 = L.y - 0.5f * L.w; Lx1 = L.x; Ly1 = L.y;
        } else {
            Lx0 = 0.5f * (L.x - L.z); Ly0 = 0.5f * (L.y - L.w);
            Lx1 = L.x - 0.5f * L.z;   Ly1 = L.y - 0.5f * L.w;
        }

        float lxs[5] = {0.5f * (Lx0 + Lx1), Lx0, Lx0, Lx1, Lx1};
        float lys[5] = {0.5f * (Ly0 + Ly1), Ly0, Ly1, Ly0, Ly1};
        float pxs[5] = {0.5f * (Px0 + Px1), Px0, Px0, Px1, Px1};
        float pys[5] = {0.5f * (Py0 + Py1), Py0, Py1, Py0, Py1};
        float txs[5] = {0.5f * (Tx0 + Tx1), Tx0, Tx0, Tx1, Tx1};
        float tys[5] = {0.5f * (Ty0 + Ty1), Ty0, Ty1, Ty0, Ty1};

        #pragma unroll
        for (int k = 0; k < 5; ++k) {
            float pdx = pxs[k] - lxs[k], pdy = pys[k] - lys[k];
            float tdx = txs[k] - lxs[k], tdy = tys[k] - lys[k];
            float p2  = pdx * pdx + pdy * pdy;
            float t2  = tdx * tdx + tdy * tdy;
            float dot = pdx * tdx + pdy * tdy;
            float inv = rsqrtf(p2 * t2);   // ref's +1e-6 eps shifts cos by <=1e-5: within budget
            float cosang = dot * inv;
            cosang = fminf(1.0f, fmaxf(-1.0f, cosang));
            acc += fast_acos(cosang);
        }
    }
    #pragma unroll
    for (int off = 32; off > 0; off >>= 1) acc += __shfl_down(acc, off, 64);
    int lane = threadIdx.x & 63, w = threadIdx.x >> 6;
    if (lane == 0) smem[w] = acc;
    __syncthreads();
    if (threadIdx.x == 0) {
        float r = 0.f;
        #pragma unroll
        for (int i = 0; i < BS / 64; ++i) r += smem[i];
        partials[blockIdx.x] = r;
    }
}

__global__ void out_kernel(const float* __restrict__ outputs,
                           const float* __restrict__ targets,
                           const float* __restrict__ partials,
                           float* __restrict__ out,
                           int n, int P, float inv_p) {
    // Every block redundantly reduces the NB1 partials (8 KB, L2-resident)
    // to the direction-loss scalar — removes the separate finalize launch.
    __shared__ double dsm[BS / 64];
    __shared__ float c_sh;
    double dacc = 0.0;
    #pragma unroll
    for (int i = 0; i < NB1 / BS; ++i)
        dacc += (double)partials[threadIdx.x + i * BS];
    #pragma unroll
    for (int off = 32; off > 0; off >>= 1) dacc += __shfl_down(dacc, off, 64);
    int lane = threadIdx.x & 63, w = threadIdx.x >> 6;
    if (lane == 0) dsm[w] = dacc;
    __syncthreads();
    if (threadIdx.x == 0) {
        double tot = dsm[0] + dsm[1] + dsm[2] + dsm[3];
        c_sh = (float)(0.01 * 0.2 * tot / ((double)P * 15.0));
    }
    __syncthreads();
    float c = c_sh;

    long long stride = (long long)gridDim.x * blockDim.x;
    for (long long i = (long long)blockIdx.x * blockDim.x + threadIdx.x; i < n; i += stride) {
        const float4 O = *reinterpret_cast<const float4*>(outputs + i * 4);
        const float4 D = *reinterpret_cast<const float4*>(targets + i * 8 + 4);
        float s = 0.f;
        {
            float d = O.x - D.x, ad = fabsf(d);
            s += (ad < 1.f) ? 0.5f * d * d : ad - 0.5f;
        }
        {
            float d = O.y - D.y, ad = fabsf(d);
            s += (ad < 1.f) ? 0.5f * d * d : ad - 0.5f;
        }
        {
            float d = O.z - D.z, ad = fabsf(d);
            s += (ad < 1.f) ? 0.5f * d * d : ad - 0.5f;
        }
        {
            float d = O.w - D.w, ad = fabsf(d);
            s += (ad < 1.f) ? 0.5f * d * d : ad - 0.5f;
        }
        out[i] = 0.99f * s * inv_p + c;
    }
}

extern "C" void kernel_launch(void* const* d_in, const int* in_sizes, int n_in,
                              void* d_out, int out_size, void* d_ws, size_t ws_size,
                              hipStream_t stream) {
    const float* outputs = (const float*)d_in[0];
    const float* targets = (const float*)d_in[1];
    float* out = (float*)d_out;
    float* partials = (float*)d_ws;     // NB1 floats

    const int T = 16, F_DIR = 15;
    int P  = in_sizes[0] / (T * 4);     // 200000
    int n1 = F_DIR * P;                 // 3,000,000 (t,p) pairs
    int n3 = out_size;                  // 16 * P

    dir_partials<<<NB1, BS, 0, stream>>>(outputs, targets, partials, n1, P);

    int nb3 = (n3 + BS - 1) / BS;
    if (nb3 > 2048) nb3 = 2048;
    out_kernel<<<nb3, BS, 0, stream>>>(outputs, targets, partials, out, n3, P, 1.0f / (float)P);
}